// Round 1
// baseline (597.501 us; speedup 1.0000x reference)
//
#include <hip/hip_runtime.h>

#define HIDDEN 128
#define TSTEPS 512
#define NFUT 50
#define BR 16          // batch rows per block
#define THREADS 512    // 8 waves
#define HPITCH 136     // h row pitch in bf16 elems (128 + 8 pad -> conflict-free b128 reads)

typedef __bf16 bf16x8 __attribute__((ext_vector_type(8)));
typedef float floatx4 __attribute__((ext_vector_type(4)));

#if defined(__has_builtin)
#  if __has_builtin(__builtin_amdgcn_exp2f)
#    define EXP2F(x) __builtin_amdgcn_exp2f(x)
#  else
#    define EXP2F(x) exp2f(x)
#  endif
#  if __has_builtin(__builtin_amdgcn_rcpf)
#    define RCPF(x) __builtin_amdgcn_rcpf(x)
#  else
#    define RCPF(x) (1.0f / (x))
#  endif
#else
#  define EXP2F(x) exp2f(x)
#  define RCPF(x) (1.0f / (x))
#endif

__device__ __forceinline__ float fast_sigmoid(float x) {
    return RCPF(1.0f + EXP2F(-1.4426950408889634f * x));
}
__device__ __forceinline__ float fast_tanh(float x) {
    return 2.0f * RCPF(1.0f + EXP2F(-2.8853900817779268f * x)) - 1.0f;
}

__global__ __launch_bounds__(THREADS, 2)
void lstm_forecast_kernel(const float* __restrict__ x,
                          const float* __restrict__ W_ih,
                          const float* __restrict__ W_hh,
                          const float* __restrict__ b_ih,
                          const float* __restrict__ b_hh,
                          const float* __restrict__ fc_w,
                          const float* __restrict__ fc_b,
                          float* __restrict__ out) {
    // LDS: 64KB x + 2*4.25KB h(dbuf) + small  ~= 74KB -> 1 block/CU
    __shared__ __align__(16) float  x_lds[BR * 2 * TSTEPS];     // [16][512][2]
    __shared__ __align__(16) __bf16 h_lds[2][BR * HPITCH];      // double-buffered h
    __shared__ float xcur[BR * 2];
    __shared__ float ypart[BR * 2 * 8];

    const int tid  = threadIdx.x;
    const int wave = tid >> 6;
    const int lane = tid & 63;
    const int quad = lane >> 4;
    const int l15  = lane & 15;
    const int rb   = blockIdx.x * BR;

    // ---- stage x into LDS (coalesced float4) ----
    {
        const float4* xg = (const float4*)x;
        float4* xl = (float4*)x_lds;
        for (int i = tid; i < BR * 256; i += THREADS) {
            const int row = i >> 8;       // 256 float4 per row
            const int c4  = i & 255;
            xl[row * 256 + c4] = xg[(size_t)(rb + row) * 256 + c4];
        }
    }
    // zero h buffer 0 (h_0 = 0)
    for (int i = tid; i < BR * HPITCH; i += THREADS) h_lds[0][i] = (__bf16)0.0f;

    // ---- W_hh fragments -> registers (weights stationary across all 562 steps) ----
    // wave owns hidden units u = wave*16 + l15; gate tile g covers col cg = g*128 + u
    bf16x8 bfrag[4][4];
    float wih0[4], wih1[4], bsum[4];
    const int u = wave * 16 + l15;
#pragma unroll
    for (int g = 0; g < 4; ++g) {
        const int cg = g * HIDDEN + u;
        wih0[g] = W_ih[cg * 2 + 0];
        wih1[g] = W_ih[cg * 2 + 1];
        bsum[g] = b_ih[cg] + b_hh[cg];
#pragma unroll
        for (int ks = 0; ks < 4; ++ks) {
            const int k0 = ks * 32 + quad * 8;
            const float* wp = W_hh + (size_t)cg * HIDDEN + k0;
            bf16x8 bb;
#pragma unroll
            for (int j = 0; j < 8; ++j) bb[j] = (__bf16)wp[j];
            bfrag[g][ks] = bb;
        }
    }

    // fc weights for forecast y phase: thread tid<256 -> (r=tid>>4, o=(tid>>3)&1, q=tid&7)
    float fcw[16];
    {
        const int o = (tid >> 3) & 1;
        const int q = tid & 7;
#pragma unroll
        for (int j = 0; j < 16; ++j) fcw[j] = fc_w[o * HIDDEN + q * 16 + j];
    }
    const float fcb0 = fc_b[tid & 1];  // reduce threads use o = tid&1

    float cstate[4] = {0.f, 0.f, 0.f, 0.f};

    __syncthreads();

    for (int t = 0; t < TSTEPS + NFUT; ++t) {
        const int rbuf = t & 1;
        const int wbuf = rbuf ^ 1;
        const bool fore = (t >= TSTEPS);

        if (fore) {
            // y = h @ fc_w^T + fc_b  (from current h, before cell update)
            const int f = t - TSTEPS;
            if (tid < 256) {
                const int r = tid >> 4;
                const int q = tid & 7;
                const __bf16* hp = &h_lds[rbuf][r * HPITCH + q * 16];
                float s = 0.f;
#pragma unroll
                for (int j = 0; j < 16; ++j) s += (float)hp[j] * fcw[j];
                ypart[tid] = s;
            }
            __syncthreads();
            if (tid < 32) {
                const int r = tid >> 1;
                const int o = tid & 1;
                float yv = fcb0;
#pragma unroll
                for (int q = 0; q < 8; ++q) yv += ypart[r * 16 + o * 8 + q];
                out[(size_t)(rb + r) * (2 * NFUT) + f * 2 + o] = yv;
                xcur[r * 2 + o] = yv;
            }
            __syncthreads();
        }

        // ---- gates = h @ W_hh^T + bias (+ x @ W_ih^T) ----
        bf16x8 afrag[4];  // A[m=l15][k = ks*32 + quad*8 + j]
#pragma unroll
        for (int ks = 0; ks < 4; ++ks)
            afrag[ks] = *(const bf16x8*)&h_lds[rbuf][l15 * HPITCH + ks * 32 + quad * 8];

        floatx4 acc[4];
#pragma unroll
        for (int g = 0; g < 4; ++g) acc[g] = (floatx4){bsum[g], bsum[g], bsum[g], bsum[g]};
#pragma unroll
        for (int g = 0; g < 4; ++g)
#pragma unroll
            for (int ks = 0; ks < 4; ++ks)
                acc[g] = __builtin_amdgcn_mfma_f32_16x16x32_bf16(afrag[ks], bfrag[g][ks], acc[g], 0, 0, 0);

        // rows owned by this lane: r = quad*4 + reg ; cols: this lane's u per gate
        float xv0[4], xv1[4];
#pragma unroll
        for (int reg = 0; reg < 4; ++reg) {
            const int r = quad * 4 + reg;
            if (!fore) {
                xv0[reg] = x_lds[r * (2 * TSTEPS) + t * 2 + 0];
                xv1[reg] = x_lds[r * (2 * TSTEPS) + t * 2 + 1];
            } else {
                xv0[reg] = xcur[r * 2 + 0];
                xv1[reg] = xcur[r * 2 + 1];
            }
        }
#pragma unroll
        for (int reg = 0; reg < 4; ++reg) {
            const float gi = acc[0][reg] + xv0[reg] * wih0[0] + xv1[reg] * wih1[0];
            const float gf = acc[1][reg] + xv0[reg] * wih0[1] + xv1[reg] * wih1[1];
            const float gg = acc[2][reg] + xv0[reg] * wih0[2] + xv1[reg] * wih1[2];
            const float go = acc[3][reg] + xv0[reg] * wih0[3] + xv1[reg] * wih1[3];
            const float cn = fast_sigmoid(gf) * cstate[reg] + fast_sigmoid(gi) * fast_tanh(gg);
            const float hn = fast_sigmoid(go) * fast_tanh(cn);
            cstate[reg] = cn;
            h_lds[wbuf][(quad * 4 + reg) * HPITCH + u] = (__bf16)hn;
        }
        __syncthreads();
    }
}

extern "C" void kernel_launch(void* const* d_in, const int* in_sizes, int n_in,
                              void* d_out, int out_size, void* d_ws, size_t ws_size,
                              hipStream_t stream) {
    const float* x    = (const float*)d_in[0];
    const float* W_ih = (const float*)d_in[1];
    const float* W_hh = (const float*)d_in[2];
    const float* b_ih = (const float*)d_in[3];
    const float* b_hh = (const float*)d_in[4];
    const float* fc_w = (const float*)d_in[5];
    const float* fc_b = (const float*)d_in[6];
    float* out = (float*)d_out;

    const int B = in_sizes[0] / (TSTEPS * 2);   // 4096
    const int grid = B / BR;                    // 256 blocks, 1 per CU
    lstm_forecast_kernel<<<grid, THREADS, 0, stream>>>(x, W_ih, W_hh, b_ih, b_hh, fc_w, fc_b, out);
}

// Round 2
// 534.346 us; speedup vs baseline: 1.1182x; 1.1182x over previous
//
#include <hip/hip_runtime.h>

#define HIDDEN 128
#define TSTEPS 512
#define NFUT 50
#define BR 16          // batch rows per block
#define THREADS 512    // 8 waves
#define HPITCH 136     // h row pitch in bf16 (128+8 pad)

typedef __bf16 bf16x8 __attribute__((ext_vector_type(8)));
typedef float floatx4 __attribute__((ext_vector_type(4)));

union B8 { int4 i; bf16x8 v; };

#if defined(__has_builtin)
#  if __has_builtin(__builtin_amdgcn_exp2f)
#    define EXP2F(x) __builtin_amdgcn_exp2f(x)
#  else
#    define EXP2F(x) exp2f(x)
#  endif
#  if __has_builtin(__builtin_amdgcn_rcpf)
#    define RCPF(x) __builtin_amdgcn_rcpf(x)
#  else
#    define RCPF(x) (1.0f / (x))
#  endif
#else
#  define EXP2F(x) exp2f(x)
#  define RCPF(x) (1.0f / (x))
#endif

#define L2E  1.4426950408889634f
#define L2E2 2.8853900817779268f

__global__ __launch_bounds__(THREADS, 2)
void lstm_forecast_kernel(const float* __restrict__ x,
                          const float* __restrict__ W_ih,
                          const float* __restrict__ W_hh,
                          const float* __restrict__ b_ih,
                          const float* __restrict__ b_hh,
                          const float* __restrict__ fc_w,
                          const float* __restrict__ fc_b,
                          float* __restrict__ out) {
    // LDS: xa 64KB + h 8.5KB + fcw 1KB  ~= 74KB -> 1 block/CU (grid-limited anyway)
    __shared__ __align__(16) uint2  xa[TSTEPS * BR];        // (x0h,x1h),(x0r,x1r) bf16 splits
    __shared__ __align__(16) __bf16 h_lds[2][BR * HPITCH];  // double-buffered h
    __shared__ __align__(16) float  fcw_lds[2][HIDDEN];

    const int tid  = threadIdx.x;
    const int wave = tid >> 6;
    const int lane = tid & 63;
    const int quad = lane >> 4;
    const int l15  = lane & 15;
    const int rb   = blockIdx.x * BR;

    // ---- stage fc_w (fp32) ----
    if (tid < 256) fcw_lds[tid >> 7][tid & 127] = fc_w[tid];

    // ---- stage x as bf16 hi/lo splits: xa[t][row] ----
    {
        const int row = tid & 15;
        for (int tb = tid >> 4; tb < TSTEPS; tb += THREADS >> 4) {
            float2 xv = *(const float2*)&x[(size_t)(rb + row) * (2 * TSTEPS) + tb * 2];
            __bf16 x0h = (__bf16)xv.x, x1h = (__bf16)xv.y;
            __bf16 x0r = (__bf16)(xv.x - (float)x0h);
            __bf16 x1r = (__bf16)(xv.y - (float)x1h);
            uint2 d;
            d.x = (unsigned)__builtin_bit_cast(unsigned short, x0h) |
                  ((unsigned)__builtin_bit_cast(unsigned short, x1h) << 16);
            d.y = (unsigned)__builtin_bit_cast(unsigned short, x0r) |
                  ((unsigned)__builtin_bit_cast(unsigned short, x1r) << 16);
            xa[tb * BR + row] = d;
        }
    }
    for (int i = tid; i < BR * HPITCH; i += THREADS) h_lds[0][i] = (__bf16)0.0f;

    // ---- weights -> registers ----
    bf16x8 bfrag[4][4];   // W_hh (later W_eff) fragments
    B8 bfx[4];            // x+bias MFMA B-fragments (quad0 slots)
    float wih0[4], wih1[4], bsum[4];
    const int u = wave * 16 + l15;
    const float fcb0 = fc_b[0], fcb1 = fc_b[1];
#pragma unroll
    for (int g = 0; g < 4; ++g) {
        const int cg = g * HIDDEN + u;
        wih0[g] = W_ih[cg * 2 + 0];
        wih1[g] = W_ih[cg * 2 + 1];
        bsum[g] = b_ih[cg] + b_hh[cg];
#pragma unroll
        for (int ks = 0; ks < 4; ++ks) {
            const float* wp = W_hh + (size_t)cg * HIDDEN + ks * 32 + quad * 8;
            bf16x8 bb;
#pragma unroll
            for (int j = 0; j < 8; ++j) bb[j] = (__bf16)wp[j];
            bfrag[g][ks] = bb;
        }
        B8 t; t.i = make_int4(0, 0, 0, 0);
        if (quad == 0) {
            __bf16 w0h = (__bf16)wih0[g], w1h = (__bf16)wih1[g];
            __bf16 w0l = (__bf16)(wih0[g] - (float)w0h);
            __bf16 w1l = (__bf16)(wih1[g] - (float)w1h);
            __bf16 bh  = (__bf16)bsum[g];
            __bf16 bl  = (__bf16)(bsum[g] - (float)bh);
            bf16x8 bv = {w0h, w1h, bh, bl, w0h, w1h, w0l, w1l};
            t.v = bv;
        }
        bfx[g] = t;
    }

    const unsigned qm    = (quad == 0) ? 0xFFFFFFFFu : 0u;
    const unsigned onesq = 0x3F803F80u & qm;  // bf16(1.0) x2, quad0 only

    float cst[4] = {0.f, 0.f, 0.f, 0.f};

    // elementwise: 5 exp + 3 rcp per state (shared-reciprocal trick)
    auto ew = [&](floatx4 a0, floatx4 a1, floatx4 a2, floatx4 a3, __bf16* hd) {
#pragma unroll
        for (int reg = 0; reg < 4; ++reg) {
            const float gi = a0[reg], gf = a1[reg], gg = a2[reg], go = a3[reg];
            const float ea = EXP2F(-L2E * gi);
            const float eb = EXP2F(-L2E2 * gg);
            const float R  = RCPF((1.f + ea) * (1.f + eb));
            const float ig = (1.f - eb) * R;               // sigmoid(i)*tanh(g)
            const float sf = RCPF(1.f + EXP2F(-L2E * gf)); // sigmoid(f)
            const float cn = sf * cst[reg] + ig;
            cst[reg] = cn;
            const float cc = fmaxf(cn, -30.f);             // exp-overflow guard (tanh saturated)
            const float ed = EXP2F(-L2E2 * cc);
            const float eo = EXP2F(-L2E * go);
            const float R2 = RCPF((1.f + eo) * (1.f + ed));
            const float hn = (1.f - ed) * R2;              // sigmoid(o)*tanh(c)
            hd[(quad * 4 + reg) * HPITCH + u] = (__bf16)hn;
        }
    };

    auto cellE = [&](const __bf16* hs, __bf16* hd, int t) {
        const uint2 xd = xa[t * BR + l15];                 // quad-broadcast, conflict-free
        B8 xf; xf.i = make_int4((int)(xd.x & qm), (int)onesq, (int)(xd.y & qm), (int)(xd.x & qm));
        bf16x8 af[4];
#pragma unroll
        for (int ks = 0; ks < 4; ++ks)
            af[ks] = *(const bf16x8*)&hs[l15 * HPITCH + ks * 32 + quad * 8];
        const floatx4 z = {0.f, 0.f, 0.f, 0.f};
        floatx4 acc[4];
#pragma unroll
        for (int g = 0; g < 4; ++g)   // x + bias folded into MFMA, zero-C init
            acc[g] = __builtin_amdgcn_mfma_f32_16x16x32_bf16(xf.v, bfx[g].v, z, 0, 0, 0);
#pragma unroll
        for (int ks = 0; ks < 4; ++ks)
#pragma unroll
            for (int g = 0; g < 4; ++g)
                acc[g] = __builtin_amdgcn_mfma_f32_16x16x32_bf16(af[ks], bfrag[g][ks], acc[g], 0, 0, 0);
        ew(acc[0], acc[1], acc[2], acc[3], hd);
        __syncthreads();
    };

    __syncthreads();

    // ================= encode: 512 steps =================
    for (int t = 0; t < TSTEPS; t += 2) {
        cellE(h_lds[0], h_lds[1], t);
        cellE(h_lds[1], h_lds[0], t + 1);
    }

    // ========== transition: fold fc into weights =========
    // W_eff = W_hh + W_ih*fc_w ; b_eff = b + W_ih*fc_b   (y eliminated from recurrence)
    float bs2[4];
#pragma unroll
    for (int g = 0; g < 4; ++g) {
        bs2[g] = bsum[g] + wih0[g] * fcb0 + wih1[g] * fcb1;
#pragma unroll
        for (int ks = 0; ks < 4; ++ks) {
            const int k0 = ks * 32 + quad * 8;
            bf16x8 bb = bfrag[g][ks];
#pragma unroll
            for (int j = 0; j < 8; ++j) {
                const float wv = (float)bb[j] + wih0[g] * fcw_lds[0][k0 + j]
                                             + wih1[g] * fcw_lds[1][k0 + j];
                bb[j] = (__bf16)wv;
            }
            bfrag[g][ks] = bb;
        }
    }

    auto cellF = [&](const __bf16* hs, __bf16* hd) {
        bf16x8 af[4];
#pragma unroll
        for (int ks = 0; ks < 4; ++ks)
            af[ks] = *(const bf16x8*)&hs[l15 * HPITCH + ks * 32 + quad * 8];
        floatx4 acc[4];
#pragma unroll
        for (int g = 0; g < 4; ++g)
            acc[g] = (floatx4){bs2[g], bs2[g], bs2[g], bs2[g]};  // exact fp32 bias
#pragma unroll
        for (int ks = 0; ks < 4; ++ks)
#pragma unroll
            for (int g = 0; g < 4; ++g)
                acc[g] = __builtin_amdgcn_mfma_f32_16x16x32_bf16(af[ks], bfrag[g][ks], acc[g], 0, 0, 0);
        ew(acc[0], acc[1], acc[2], acc[3], hd);
        __syncthreads();
    };

    // y output only (no feedback): wave0 computes while others run MFMA
    auto emitY = [&](const __bf16* hs, int f) {
        if (wave == 0) {
            const int r = lane & 15, seg = lane >> 4;
            const __bf16* hp = &hs[r * HPITCH + seg * 32];
            float p0 = 0.f, p1 = 0.f;
#pragma unroll
            for (int js = 0; js < 4; ++js) {
                bf16x8 hv = *(const bf16x8*)&hp[js * 8];
                const float4* f0 = (const float4*)&fcw_lds[0][seg * 32 + js * 8];
                const float4* f1 = (const float4*)&fcw_lds[1][seg * 32 + js * 8];
                float4 a0 = f0[0], b0 = f0[1], a1 = f1[0], b1 = f1[1];
                p0 += (float)hv[0]*a0.x + (float)hv[1]*a0.y + (float)hv[2]*a0.z + (float)hv[3]*a0.w
                    + (float)hv[4]*b0.x + (float)hv[5]*b0.y + (float)hv[6]*b0.z + (float)hv[7]*b0.w;
                p1 += (float)hv[0]*a1.x + (float)hv[1]*a1.y + (float)hv[2]*a1.z + (float)hv[3]*a1.w
                    + (float)hv[4]*b1.x + (float)hv[5]*b1.y + (float)hv[6]*b1.z + (float)hv[7]*b1.w;
            }
            p0 += __shfl_xor(p0, 16); p0 += __shfl_xor(p0, 32);
            p1 += __shfl_xor(p1, 16); p1 += __shfl_xor(p1, 32);
            if (seg == 0) {
                float* op = &out[(size_t)(rb + r) * (2 * NFUT) + f * 2];
                op[0] = p0 + fcb0;
                op[1] = p1 + fcb1;
            }
        }
    };

    // ================= forecast: 50 steps ================
    for (int f = 0; f < NFUT; f += 2) {
        emitY(h_lds[0], f);
        cellF(h_lds[0], h_lds[1]);
        emitY(h_lds[1], f + 1);
        cellF(h_lds[1], h_lds[0]);
    }
}

extern "C" void kernel_launch(void* const* d_in, const int* in_sizes, int n_in,
                              void* d_out, int out_size, void* d_ws, size_t ws_size,
                              hipStream_t stream) {
    const float* x    = (const float*)d_in[0];
    const float* W_ih = (const float*)d_in[1];
    const float* W_hh = (const float*)d_in[2];
    const float* b_ih = (const float*)d_in[3];
    const float* b_hh = (const float*)d_in[4];
    const float* fc_w = (const float*)d_in[5];
    const float* fc_b = (const float*)d_in[6];
    float* out = (float*)d_out;

    const int B = in_sizes[0] / (TSTEPS * 2);   // 4096
    const int grid = B / BR;                    // 256 blocks, 1 per CU
    lstm_forecast_kernel<<<grid, THREADS, 0, stream>>>(x, W_ih, W_hh, b_ih, b_hh, fc_w, fc_b, out);
}